// Round 4
// baseline (481.982 us; speedup 1.0000x reference)
//
#include <hip/hip_runtime.h>

// CRAFT OHEM loss, round 4.
// R3 -> R4: no loss materialization (pure-read streams); single 2048-bin
// count+sum histogram pass gives threshold bin AND sum-above directly;
// pass2 is compact-only; refinement is one 64-block in-LDS kernel.
// 6 launches total.

constexpr int   BATCH   = 32;
constexpr int   NPS     = 768 * 768;            // 589824
constexpr int   CH2     = BATCH * 2;            // 64
constexpr int   EPB     = 16384;                // pixels per block
constexpr int   BX      = NPS / EPB;            // 36
constexpr float POS_THR_F = 0.1f;
constexpr unsigned TOPK_NO_POS = 500u;
constexpr int   NB1     = 2048;                 // stage-1 bins: bits>>19 (max 2031 for v<1)
constexpr int   CAP     = 131072;               // global compact buffer per channel (~14x margin)
constexpr int   CAPB    = 1024;                 // LDS staging per channel per block

// ---------------------------------------------------------------------------
// Pass 1: loss (recomputed, never stored) + positive stats + 2048-bin
// count+sum histogram per channel.
// ---------------------------------------------------------------------------
__global__ __launch_bounds__(256, 4) void k_hist(
    const float4* __restrict__ pred4,
    const float4* __restrict__ reg4,
    const float4* __restrict__ aff4,
    unsigned* __restrict__ h1c, float* __restrict__ h1s,
    unsigned* __restrict__ pcnt, float* __restrict__ psum)
{
    __shared__ unsigned sc0[NB1], sc1[NB1];
    __shared__ float    ss0[NB1], ss1[NB1];
    __shared__ unsigned wpc[8];
    __shared__ float    wps[8];
    for (int j = threadIdx.x; j < NB1; j += 256) { sc0[j]=0u; sc1[j]=0u; ss0[j]=0.f; ss1[j]=0.f; }
    __syncthreads();

    const int  b   = blockIdx.y;
    const int  tid = threadIdx.x;
    constexpr int ITERS = EPB / 1024;            // 16
    long idx4 = (((long)b * NPS + (long)blockIdx.x * EPB) >> 2) + tid;

    unsigned pc0 = 0, pc1 = 0;
    float    ps0 = 0.f, ps1 = 0.f;

    float4 r = reg4[idx4], a = aff4[idx4];
    float4 pA = pred4[idx4 * 2], pB = pred4[idx4 * 2 + 1];

    for (int i = 0; i < ITERS; ++i) {
        float4 rn, an, pAn, pBn;
        if (i + 1 < ITERS) {
            const long nx = idx4 + 256;
            rn = reg4[nx]; an = aff4[nx]; pAn = pred4[nx * 2]; pBn = pred4[nx * 2 + 1];
        }
#define DO_PIX(RR, AA, PG, PA) do {                                           \
        float d0 = (PG) - (RR); float v0 = d0 * d0;                           \
        if ((RR) >= POS_THR_F) { pc0++; ps0 += v0; }                          \
        else { unsigned ky = __float_as_uint(v0) >> 19;                       \
               atomicAdd(&sc0[ky], 1u); unsafeAtomicAdd(&ss0[ky], v0); }      \
        float d1 = (PA) - (AA); float v1 = d1 * d1;                           \
        if ((AA) >= POS_THR_F) { pc1++; ps1 += v1; }                          \
        else { unsigned ky = __float_as_uint(v1) >> 19;                       \
               atomicAdd(&sc1[ky], 1u); unsafeAtomicAdd(&ss1[ky], v1); }      \
    } while (0)
        DO_PIX(r.x, a.x, pA.x, pA.y);
        DO_PIX(r.y, a.y, pA.z, pA.w);
        DO_PIX(r.z, a.z, pB.x, pB.y);
        DO_PIX(r.w, a.w, pB.z, pB.w);
#undef DO_PIX
        idx4 += 256; r = rn; a = an; pA = pAn; pB = pBn;
    }
    __syncthreads();

    for (int j = tid; j < NB1; j += 256) {
        unsigned c0 = sc0[j];
        if (c0) { atomicAdd(&h1c[(b*2+0)*NB1 + j], c0); unsafeAtomicAdd(&h1s[(b*2+0)*NB1 + j], ss0[j]); }
        unsigned c1 = sc1[j];
        if (c1) { atomicAdd(&h1c[(b*2+1)*NB1 + j], c1); unsafeAtomicAdd(&h1s[(b*2+1)*NB1 + j], ss1[j]); }
    }
    for (int o = 32; o > 0; o >>= 1) {
        pc0 += __shfl_down(pc0, o); ps0 += __shfl_down(ps0, o);
        pc1 += __shfl_down(pc1, o); ps1 += __shfl_down(ps1, o);
    }
    const int wid = tid >> 6, lane = tid & 63;
    if (lane == 0) { wpc[wid] = pc0; wps[wid] = ps0; wpc[4+wid] = pc1; wps[4+wid] = ps1; }
    __syncthreads();
    if (tid == 0) {
        unsigned t0 = 0, t1 = 0; float s0 = 0.f, s1 = 0.f;
        for (int q = 0; q < 4; ++q) { t0 += wpc[q]; s0 += wps[q]; t1 += wpc[4+q]; s1 += wps[4+q]; }
        atomicAdd(&pcnt[b*2+0], t0); unsafeAtomicAdd(&psum[b*2+0], s0);
        atomicAdd(&pcnt[b*2+1], t1); unsafeAtomicAdd(&psum[b*2+1], s1);
    }
}

// ---------------------------------------------------------------------------
// Block suffix selects (256 threads). Work on global or LDS pointers.
// ---------------------------------------------------------------------------
template<int NBINS>
__device__ __forceinline__ void select_counts(
    const unsigned* cnt, unsigned k, unsigned& outBin, unsigned& outRem)
{
    constexpr int PER = NBINS / 256;
    const int t = threadIdx.x;
    unsigned lc[PER];
#pragma unroll
    for (int j = 0; j < PER; ++j) lc[j] = cnt[t*PER + j];
    unsigned lsum = 0;
#pragma unroll
    for (int j = 0; j < PER; ++j) lsum += lc[j];

    __shared__ unsigned part[256];
    __shared__ unsigned s_bin, s_rem;
    part[t] = lsum;
    __syncthreads();
    for (int off = 1; off < 256; off <<= 1) {
        unsigned v = (t + off < 256) ? part[t + off] : 0u;
        __syncthreads();
        part[t] += v;
        __syncthreads();
    }
    unsigned cum = (t + 1 < 256) ? part[t + 1] : 0u;
#pragma unroll
    for (int j = PER - 1; j >= 0; --j) {
        unsigned c = lc[j];
        if (cum < k && k <= cum + c) { s_bin = (unsigned)(t * PER + j); s_rem = k - cum; }
        cum += c;
    }
    __syncthreads();
    outBin = s_bin; outRem = s_rem;
}

template<int NBINS>
__device__ __forceinline__ void select_counts_sums(
    const unsigned* cnt, const float* sums,
    unsigned k, unsigned& outBin, unsigned& outRem, double& outSum)
{
    constexpr int PER = NBINS / 256;
    const int t = threadIdx.x;
    unsigned lc[PER]; float lf[PER];
#pragma unroll
    for (int j = 0; j < PER; ++j) { lc[j] = cnt[t*PER + j]; lf[j] = sums[t*PER + j]; }
    unsigned lsum = 0;
#pragma unroll
    for (int j = 0; j < PER; ++j) lsum += lc[j];

    __shared__ unsigned part[256];
    __shared__ unsigned s_bin, s_rem;
    __shared__ double   wsum[4];
    part[t] = lsum;
    __syncthreads();
    for (int off = 1; off < 256; off <<= 1) {
        unsigned v = (t + off < 256) ? part[t + off] : 0u;
        __syncthreads();
        part[t] += v;
        __syncthreads();
    }
    unsigned cum = (t + 1 < 256) ? part[t + 1] : 0u;
#pragma unroll
    for (int j = PER - 1; j >= 0; --j) {
        unsigned c = lc[j];
        if (cum < k && k <= cum + c) { s_bin = (unsigned)(t * PER + j); s_rem = k - cum; }
        cum += c;
    }
    __syncthreads();
    const unsigned bin = s_bin;
    double ds = 0.0;
#pragma unroll
    for (int j = 0; j < PER; ++j)
        if ((unsigned)(t * PER + j) > bin) ds += (double)lf[j];
    for (int o = 32; o > 0; o >>= 1) ds += __shfl_down(ds, o);
    const int wid = t >> 6, lane = t & 63;
    if (lane == 0) wsum[wid] = ds;
    __syncthreads();
    if (t == 0) ds = wsum[0] + wsum[1] + wsum[2] + wsum[3];
    outBin = bin; outRem = s_rem; outSum = ds;
}

// scan1: per channel -> k, posi, T1, rem1, sumAbove (f64, from histogram sums)
__global__ __launch_bounds__(256) void k_scan1(
    const unsigned* __restrict__ h1c, const float* __restrict__ h1s,
    const unsigned* __restrict__ pcnt, const float* __restrict__ psum,
    unsigned* __restrict__ T1, unsigned* __restrict__ rem1,
    unsigned* __restrict__ kk, float* __restrict__ posi,
    double* __restrict__ sumAbove)
{
    const int idx = blockIdx.x;
    const unsigned p  = pcnt[idx];
    const unsigned nn = (unsigned)NPS - p;
    const unsigned k  = p ? ((nn < 3u*p) ? nn : 3u*p) : TOPK_NO_POS;
    if (threadIdx.x == 0) {
        kk[idx]   = k;
        posi[idx] = p ? (psum[idx] / (float)p) : 0.0f;
    }
    if (k == 0u) {
        if (threadIdx.x == 0) { T1[idx] = 0xFFFFFFFFu; rem1[idx] = 0u; sumAbove[idx] = 0.0; }
        return;
    }
    unsigned bin, rem; double s;
    select_counts_sums<NB1>(h1c + idx*NB1, h1s + idx*NB1, k, bin, rem, s);
    if (threadIdx.x == 0) { T1[idx] = bin; rem1[idx] = rem; sumAbove[idx] = s; }
}

// ---------------------------------------------------------------------------
// Pass 2: compact-only. Recompute loss, stage T1-bin members in LDS, flush with
// one global atomic per channel per block.
// ---------------------------------------------------------------------------
__global__ __launch_bounds__(256, 4) void k_compact(
    const float4* __restrict__ pred4,
    const float4* __restrict__ reg4,
    const float4* __restrict__ aff4,
    const unsigned* __restrict__ T1,
    float* __restrict__ cbuf, unsigned* __restrict__ ccnt)
{
    __shared__ float    lb0[CAPB], lb1[CAPB];
    __shared__ unsigned lcnt[2];
    __shared__ unsigned sbase[2];
    if (threadIdx.x < 2) lcnt[threadIdx.x] = 0u;
    __syncthreads();

    const int b = blockIdx.y;
    const unsigned t1r = T1[b*2+0], t1a = T1[b*2+1];
    const int tid = threadIdx.x, lane = tid & 63;
    float*    gb0 = cbuf + (size_t)(b*2+0) * CAP;
    float*    gb1 = cbuf + (size_t)(b*2+1) * CAP;
    unsigned* gc0 = ccnt + b*2+0;
    unsigned* gc1 = ccnt + b*2+1;

    auto proc = [&](float tgt, float pg, unsigned t1,
                    unsigned* lcnt_p, float* lbuf, unsigned* gcnt, float* gbuf) {
        if (tgt >= POS_THR_F) return;            // positive pixel
        const float d = pg - tgt;
        const float v = d * d;
        if ((__float_as_uint(v) >> 19) != t1) return;
        const unsigned long long m = __ballot(true);
        const int ldr = __ffsll(m) - 1;
        const unsigned pre = (unsigned)__popcll(m & ((1ull << lane) - 1ull));
        unsigned base = 0;
        if (lane == ldr) base = atomicAdd(lcnt_p, (unsigned)__popcll(m));  // LDS
        base = __shfl(base, ldr);
        const unsigned ix = base + pre;
        if (ix < (unsigned)CAPB) lbuf[ix] = v;
        else { unsigned g = atomicAdd(gcnt, 1u); if (g < (unsigned)CAP) gbuf[g] = v; }
    };

    constexpr int ITERS = EPB / 1024;            // 16
    long idx4 = (((long)b * NPS + (long)blockIdx.x * EPB) >> 2) + tid;
    for (int i = 0; i < ITERS; ++i) {
        float4 rn, an, pAn, pBn;
        if (i + 1 < ITERS) {
            const long nx = idx4 + 256;
            rn = reg4[nx]; an = aff4[nx]; pAn = pred4[nx * 2]; pBn = pred4[nx * 2 + 1];
        } else {
            rn = reg4[idx4]; an = aff4[idx4]; pAn = pred4[idx4*2]; pBn = pred4[idx4*2+1];
        }
        const float4 r  = (i == 0) ? reg4[idx4] : rn;   // placeholder; real pipeline below
        (void)r;
        // NOTE: simple non-pipelined loads — this kernel is branch-light and
        // mostly skips; rely on wave-level overlap.
        const float4 rr = reg4[idx4];
        const float4 aa = aff4[idx4];
        const float4 pA = pred4[idx4*2];
        const float4 pB = pred4[idx4*2+1];
        proc(rr.x, pA.x, t1r, &lcnt[0], lb0, gc0, gb0);
        proc(rr.y, pA.z, t1r, &lcnt[0], lb0, gc0, gb0);
        proc(rr.z, pB.x, t1r, &lcnt[0], lb0, gc0, gb0);
        proc(rr.w, pB.z, t1r, &lcnt[0], lb0, gc0, gb0);
        proc(aa.x, pA.y, t1a, &lcnt[1], lb1, gc1, gb1);
        proc(aa.y, pA.w, t1a, &lcnt[1], lb1, gc1, gb1);
        proc(aa.z, pB.y, t1a, &lcnt[1], lb1, gc1, gb1);
        proc(aa.w, pB.w, t1a, &lcnt[1], lb1, gc1, gb1);
        idx4 += 256;
    }
    __syncthreads();

    const unsigned lc0 = lcnt[0] < (unsigned)CAPB ? lcnt[0] : (unsigned)CAPB;
    const unsigned lc1 = lcnt[1] < (unsigned)CAPB ? lcnt[1] : (unsigned)CAPB;
    if (tid == 0)      sbase[0] = lc0 ? atomicAdd(gc0, lc0) : 0u;
    else if (tid == 1) sbase[1] = lc1 ? atomicAdd(gc1, lc1) : 0u;
    __syncthreads();
    for (unsigned i = tid; i < lc0; i += 256) {
        unsigned g = sbase[0] + i;
        if (g < (unsigned)CAP) gb0[g] = lb0[i];
    }
    for (unsigned i = tid; i < lc1; i += 256) {
        unsigned g = sbase[1] + i;
        if (g < (unsigned)CAP) gb1[g] = lb1[i];
    }
}

// ---------------------------------------------------------------------------
// Refine: per channel, two in-LDS histogram rounds over the compact buffer
// (bits[18:8] then bits[7:0]), exact threshold, f64 sum above it.
// ---------------------------------------------------------------------------
__global__ __launch_bounds__(256) void k_refine(
    const float* __restrict__ cbuf, const unsigned* __restrict__ ccnt,
    const unsigned* __restrict__ T1, const unsigned* __restrict__ rem1,
    const unsigned* __restrict__ kk, const float* __restrict__ posi,
    const double* __restrict__ sumAbove,
    float* __restrict__ contrib)
{
    const int ch = blockIdx.x;
    const unsigned k = kk[ch];
    if (k == 0u) {
        if (threadIdx.x == 0) contrib[ch] = posi[ch];
        return;
    }
    unsigned cnt = ccnt[ch];
    if (cnt > (unsigned)CAP) cnt = (unsigned)CAP;   // see CAP margin note
    const float* buf = cbuf + (size_t)ch * CAP;
    const int tid = threadIdx.x;

    __shared__ unsigned hA[NB1];
    __shared__ unsigned hB[256];
    __shared__ double   wsum[4];
    for (int j = tid; j < NB1; j += 256) hA[j] = 0u;
    __syncthreads();
    for (unsigned i = tid; i < cnt; i += 256) {
        const unsigned bt = __float_as_uint(buf[i]);
        atomicAdd(&hA[(bt >> 8) & 2047u], 1u);
    }
    __syncthreads();
    unsigned T2, rem2;
    select_counts<NB1>(hA, rem1[ch], T2, rem2);

    hB[tid] = 0u;
    __syncthreads();
    for (unsigned i = tid; i < cnt; i += 256) {
        const unsigned bt = __float_as_uint(buf[i]);
        if (((bt >> 8) & 2047u) == T2) atomicAdd(&hB[bt & 255u], 1u);
    }
    __syncthreads();
    unsigned T3, rem3;
    select_counts<256>(hB, rem2, T3, rem3);

    const float t = __uint_as_float((T1[ch] << 19) | (T2 << 8) | T3);
    double s = 0.0;
    for (unsigned i = tid; i < cnt; i += 256) {
        const float v = buf[i];
        if (v > t) s += (double)v;
    }
    for (int o = 32; o > 0; o >>= 1) s += __shfl_down(s, o);
    const int wid = tid >> 6, lane = tid & 63;
    if (lane == 0) wsum[wid] = s;
    __syncthreads();
    if (tid == 0) {
        const double stop = wsum[0] + wsum[1] + wsum[2] + wsum[3];
        const double nega = (sumAbove[ch] + stop + (double)rem3 * (double)t) / (double)k;
        contrib[ch] = (float)((double)posi[ch] + nega);
    }
}

__global__ void k_reduce(const float* __restrict__ contrib, float* __restrict__ out)
{
    double v = (double)contrib[threadIdx.x];
    for (int o = 32; o > 0; o >>= 1) v += __shfl_down(v, o);
    if (threadIdx.x == 0) out[0] = (float)(v / (double)BATCH);
}

// ---------------------------------------------------------------------------
extern "C" void kernel_launch(void* const* d_in, const int* in_sizes, int n_in,
                              void* d_out, int out_size, void* d_ws, size_t ws_size,
                              hipStream_t stream)
{
    (void)in_sizes; (void)n_in; (void)out_size; (void)ws_size;
    const float4* pred4 = (const float4*)d_in[0];
    const float4* reg4  = (const float4*)d_in[1];
    const float4* aff4  = (const float4*)d_in[2];

    char* w = (char*)d_ws;
    unsigned* h1c  = (unsigned*)w;                        // 64*2048 u32 = 512 KB
    float*    h1s  = (float*)(h1c + (size_t)CH2 * NB1);   // 512 KB
    unsigned* pcnt = (unsigned*)(h1s + (size_t)CH2 * NB1);
    float*    psum = (float*)(pcnt + CH2);
    unsigned* T1   = (unsigned*)(psum + CH2);
    unsigned* rem1 = T1 + CH2;
    unsigned* kk   = rem1 + CH2;
    float*    posi = (float*)(kk + CH2);
    float*    contrib = posi + CH2;
    unsigned* ccnt = (unsigned*)(contrib + CH2);
    double*   sumAbove = (double*)(ccnt + CH2);           // offset divisible by 8
    const size_t hdr_bytes = (size_t)((char*)(sumAbove + CH2) - w);  // ~1.05 MB

    float* cbuf = (float*)(w + ((size_t)2 << 20));        // 33.5 MB at +2 MB

    hipMemsetAsync(d_ws, 0, hdr_bytes, stream);

    dim3 grid(BX, BATCH);
    k_hist<<<grid, 256, 0, stream>>>(pred4, reg4, aff4, h1c, h1s, pcnt, psum);
    k_scan1<<<CH2, 256, 0, stream>>>(h1c, h1s, pcnt, psum, T1, rem1, kk, posi, sumAbove);
    k_compact<<<grid, 256, 0, stream>>>(pred4, reg4, aff4, T1, cbuf, ccnt);
    k_refine<<<CH2, 256, 0, stream>>>(cbuf, ccnt, T1, rem1, kk, posi, sumAbove, contrib);
    k_reduce<<<1, 64, 0, stream>>>(contrib, (float*)d_out);
}

// Round 5
// 397.167 us; speedup vs baseline: 1.2135x; 1.2135x over previous
//
#include <hip/hip_runtime.h>

// CRAFT OHEM loss, round 5.
// R4 -> R5: occupancy is the lever (latency-bound; dur tracked occupancy
// across R1/R3/R4). k_hist is counts-only (16.5 KB LDS, 2 atomics/pixel,
// 6 blocks/CU); sum-above returns to register accumulation in k_compact.

constexpr int   BATCH   = 32;
constexpr int   NPS     = 768 * 768;            // 589824
constexpr int   CH2     = BATCH * 2;            // 64
constexpr int   EPB     = 16384;                // pixels per block
constexpr int   BX      = NPS / EPB;            // 36
constexpr float POS_THR_F = 0.1f;
constexpr unsigned TOPK_NO_POS = 500u;
constexpr int   NB1     = 2048;                 // stage-1 bins: bits>>19
constexpr int   CAP     = 131072;               // global compact buffer per channel
constexpr int   CAPB    = 1024;                 // LDS staging per channel per block

// ---------------------------------------------------------------------------
// Pass 1: counts-only 2048-bin histogram per channel + positive stats.
// ---------------------------------------------------------------------------
__global__ __launch_bounds__(256, 6) void k_hist(
    const float4* __restrict__ pred4,
    const float4* __restrict__ reg4,
    const float4* __restrict__ aff4,
    unsigned* __restrict__ h1c,
    unsigned* __restrict__ pcnt, float* __restrict__ psum)
{
    __shared__ unsigned sc0[NB1], sc1[NB1];
    __shared__ unsigned wpc[8];
    __shared__ float    wps[8];
    for (int j = threadIdx.x; j < NB1; j += 256) { sc0[j] = 0u; sc1[j] = 0u; }
    __syncthreads();

    const int  b   = blockIdx.y;
    const int  tid = threadIdx.x;
    constexpr int ITERS = EPB / 1024;            // 16
    long idx4 = (((long)b * NPS + (long)blockIdx.x * EPB) >> 2) + tid;

    unsigned pc0 = 0, pc1 = 0;
    float    ps0 = 0.f, ps1 = 0.f;

    float4 r = reg4[idx4], a = aff4[idx4];
    float4 pA = pred4[idx4 * 2], pB = pred4[idx4 * 2 + 1];

    for (int i = 0; i < ITERS; ++i) {
        float4 rn, an, pAn, pBn;
        if (i + 1 < ITERS) {
            const long nx = idx4 + 256;
            rn = reg4[nx]; an = aff4[nx]; pAn = pred4[nx * 2]; pBn = pred4[nx * 2 + 1];
        }
#define DO_PIX(RR, AA, PG, PA) do {                                           \
        float d0 = (PG) - (RR); float v0 = d0 * d0;                           \
        if ((RR) >= POS_THR_F) { pc0++; ps0 += v0; }                          \
        else atomicAdd(&sc0[__float_as_uint(v0) >> 19], 1u);                  \
        float d1 = (PA) - (AA); float v1 = d1 * d1;                           \
        if ((AA) >= POS_THR_F) { pc1++; ps1 += v1; }                          \
        else atomicAdd(&sc1[__float_as_uint(v1) >> 19], 1u);                  \
    } while (0)
        DO_PIX(r.x, a.x, pA.x, pA.y);
        DO_PIX(r.y, a.y, pA.z, pA.w);
        DO_PIX(r.z, a.z, pB.x, pB.y);
        DO_PIX(r.w, a.w, pB.z, pB.w);
#undef DO_PIX
        idx4 += 256; r = rn; a = an; pA = pAn; pB = pBn;
    }
    __syncthreads();

    for (int j = tid; j < NB1; j += 256) {
        unsigned c0 = sc0[j];
        if (c0) atomicAdd(&h1c[(b*2+0)*NB1 + j], c0);
        unsigned c1 = sc1[j];
        if (c1) atomicAdd(&h1c[(b*2+1)*NB1 + j], c1);
    }
    for (int o = 32; o > 0; o >>= 1) {
        pc0 += __shfl_down(pc0, o); ps0 += __shfl_down(ps0, o);
        pc1 += __shfl_down(pc1, o); ps1 += __shfl_down(ps1, o);
    }
    const int wid = tid >> 6, lane = tid & 63;
    if (lane == 0) { wpc[wid] = pc0; wps[wid] = ps0; wpc[4+wid] = pc1; wps[4+wid] = ps1; }
    __syncthreads();
    if (tid == 0) {
        unsigned t0 = 0, t1 = 0; float s0 = 0.f, s1 = 0.f;
        for (int q = 0; q < 4; ++q) { t0 += wpc[q]; s0 += wps[q]; t1 += wpc[4+q]; s1 += wps[4+q]; }
        atomicAdd(&pcnt[b*2+0], t0); unsafeAtomicAdd(&psum[b*2+0], s0);
        atomicAdd(&pcnt[b*2+1], t1); unsafeAtomicAdd(&psum[b*2+1], s1);
    }
}

// ---------------------------------------------------------------------------
// Block suffix select (counts only; works on LDS or global pointers).
// ---------------------------------------------------------------------------
template<int NBINS>
__device__ __forceinline__ void select_counts(
    const unsigned* cnt, unsigned k, unsigned& outBin, unsigned& outRem)
{
    constexpr int PER = NBINS / 256;
    const int t = threadIdx.x;
    unsigned lc[PER];
#pragma unroll
    for (int j = 0; j < PER; ++j) lc[j] = cnt[t*PER + j];
    unsigned lsum = 0;
#pragma unroll
    for (int j = 0; j < PER; ++j) lsum += lc[j];

    __shared__ unsigned part[256];
    __shared__ unsigned s_bin, s_rem;
    part[t] = lsum;
    __syncthreads();
    for (int off = 1; off < 256; off <<= 1) {
        unsigned v = (t + off < 256) ? part[t + off] : 0u;
        __syncthreads();
        part[t] += v;
        __syncthreads();
    }
    unsigned cum = (t + 1 < 256) ? part[t + 1] : 0u;
#pragma unroll
    for (int j = PER - 1; j >= 0; --j) {
        unsigned c = lc[j];
        if (cum < k && k <= cum + c) { s_bin = (unsigned)(t * PER + j); s_rem = k - cum; }
        cum += c;
    }
    __syncthreads();
    outBin = s_bin; outRem = s_rem;
}

// scan1: per channel -> k, posi, T1, rem1
__global__ __launch_bounds__(256) void k_scan1(
    const unsigned* __restrict__ h1c,
    const unsigned* __restrict__ pcnt, const float* __restrict__ psum,
    unsigned* __restrict__ T1, unsigned* __restrict__ rem1,
    unsigned* __restrict__ kk, float* __restrict__ posi)
{
    const int idx = blockIdx.x;
    const unsigned p  = pcnt[idx];
    const unsigned nn = (unsigned)NPS - p;
    const unsigned k  = p ? ((nn < 3u*p) ? nn : 3u*p) : TOPK_NO_POS;
    if (threadIdx.x == 0) {
        kk[idx]   = k;
        posi[idx] = p ? (psum[idx] / (float)p) : 0.0f;
    }
    if (k == 0u) {
        if (threadIdx.x == 0) { T1[idx] = 0xFFFFFFFFu; rem1[idx] = 0u; }
        return;
    }
    unsigned bin, rem;
    select_counts<NB1>(h1c + idx*NB1, k, bin, rem);
    if (threadIdx.x == 0) { T1[idx] = bin; rem1[idx] = rem; }
}

// ---------------------------------------------------------------------------
// Pass 2: register sum of elements strictly above the T1 bin (f32 -> f64 block
// atomic) + LDS-staged compaction of T1-bin members.
// ---------------------------------------------------------------------------
__global__ __launch_bounds__(256, 6) void k_compact(
    const float4* __restrict__ pred4,
    const float4* __restrict__ reg4,
    const float4* __restrict__ aff4,
    const unsigned* __restrict__ T1,
    float* __restrict__ cbuf, unsigned* __restrict__ ccnt,
    double* __restrict__ sumAbove)
{
    __shared__ float    lb0[CAPB], lb1[CAPB];
    __shared__ unsigned lcnt[2];
    __shared__ unsigned sbase[2];
    __shared__ float    wred[8];
    if (threadIdx.x < 2) lcnt[threadIdx.x] = 0u;
    __syncthreads();

    const int b = blockIdx.y;
    const unsigned t1r = T1[b*2+0], t1a = T1[b*2+1];
    const int tid = threadIdx.x, lane = tid & 63;
    float*    gb0 = cbuf + (size_t)(b*2+0) * CAP;
    float*    gb1 = cbuf + (size_t)(b*2+1) * CAP;
    unsigned* gc0 = ccnt + b*2+0;
    unsigned* gc1 = ccnt + b*2+1;
    float rs0 = 0.f, rs1 = 0.f;

    auto proc = [&](float tgt, float pg, unsigned t1, float& rs,
                    unsigned* lcnt_p, float* lbuf, unsigned* gcnt, float* gbuf) {
        if (tgt >= POS_THR_F) return;            // positive pixel
        const float d = pg - tgt;
        const float v = d * d;
        const unsigned key = __float_as_uint(v) >> 19;
        if (key > t1) { rs += v; return; }
        if (key != t1) return;
        const unsigned long long m = __ballot(true);
        const int ldr = __ffsll(m) - 1;
        const unsigned pre = (unsigned)__popcll(m & ((1ull << lane) - 1ull));
        unsigned base = 0;
        if (lane == ldr) base = atomicAdd(lcnt_p, (unsigned)__popcll(m));  // LDS
        base = __shfl(base, ldr);
        const unsigned ix = base + pre;
        if (ix < (unsigned)CAPB) lbuf[ix] = v;
        else { unsigned g = atomicAdd(gcnt, 1u); if (g < (unsigned)CAP) gbuf[g] = v; }
    };

    constexpr int ITERS = EPB / 1024;            // 16
    long idx4 = (((long)b * NPS + (long)blockIdx.x * EPB) >> 2) + tid;

    float4 r = reg4[idx4], a = aff4[idx4];
    float4 pA = pred4[idx4 * 2], pB = pred4[idx4 * 2 + 1];

    for (int i = 0; i < ITERS; ++i) {
        float4 rn, an, pAn, pBn;
        if (i + 1 < ITERS) {
            const long nx = idx4 + 256;
            rn = reg4[nx]; an = aff4[nx]; pAn = pred4[nx * 2]; pBn = pred4[nx * 2 + 1];
        }
        proc(r.x, pA.x, t1r, rs0, &lcnt[0], lb0, gc0, gb0);
        proc(r.y, pA.z, t1r, rs0, &lcnt[0], lb0, gc0, gb0);
        proc(r.z, pB.x, t1r, rs0, &lcnt[0], lb0, gc0, gb0);
        proc(r.w, pB.z, t1r, rs0, &lcnt[0], lb0, gc0, gb0);
        proc(a.x, pA.y, t1a, rs1, &lcnt[1], lb1, gc1, gb1);
        proc(a.y, pA.w, t1a, rs1, &lcnt[1], lb1, gc1, gb1);
        proc(a.z, pB.y, t1a, rs1, &lcnt[1], lb1, gc1, gb1);
        proc(a.w, pB.w, t1a, rs1, &lcnt[1], lb1, gc1, gb1);
        idx4 += 256; r = rn; a = an; pA = pAn; pB = pBn;
    }
    __syncthreads();

    const unsigned lc0 = lcnt[0] < (unsigned)CAPB ? lcnt[0] : (unsigned)CAPB;
    const unsigned lc1 = lcnt[1] < (unsigned)CAPB ? lcnt[1] : (unsigned)CAPB;
    if (tid == 0)      sbase[0] = lc0 ? atomicAdd(gc0, lc0) : 0u;
    else if (tid == 1) sbase[1] = lc1 ? atomicAdd(gc1, lc1) : 0u;
    __syncthreads();
    for (unsigned i = tid; i < lc0; i += 256) {
        unsigned g = sbase[0] + i;
        if (g < (unsigned)CAP) gb0[g] = lb0[i];
    }
    for (unsigned i = tid; i < lc1; i += 256) {
        unsigned g = sbase[1] + i;
        if (g < (unsigned)CAP) gb1[g] = lb1[i];
    }
    for (int o = 32; o > 0; o >>= 1) { rs0 += __shfl_down(rs0, o); rs1 += __shfl_down(rs1, o); }
    const int wid = tid >> 6;
    if (lane == 0) { wred[wid] = rs0; wred[4+wid] = rs1; }
    __syncthreads();
    if (tid == 0) {
        float s0 = wred[0]+wred[1]+wred[2]+wred[3];
        float s1 = wred[4]+wred[5]+wred[6]+wred[7];
        unsafeAtomicAdd(&sumAbove[b*2+0], (double)s0);
        unsafeAtomicAdd(&sumAbove[b*2+1], (double)s1);
    }
}

// ---------------------------------------------------------------------------
// Refine: per channel, two in-LDS histogram rounds over the compact buffer
// (bits[18:8] then bits[7:0]), exact threshold, f64 sum above it.
// ---------------------------------------------------------------------------
__global__ __launch_bounds__(256) void k_refine(
    const float* __restrict__ cbuf, const unsigned* __restrict__ ccnt,
    const unsigned* __restrict__ T1, const unsigned* __restrict__ rem1,
    const unsigned* __restrict__ kk, const float* __restrict__ posi,
    const double* __restrict__ sumAbove,
    float* __restrict__ contrib)
{
    const int ch = blockIdx.x;
    const unsigned k = kk[ch];
    if (k == 0u) {
        if (threadIdx.x == 0) contrib[ch] = posi[ch];
        return;
    }
    unsigned cnt = ccnt[ch];
    if (cnt > (unsigned)CAP) cnt = (unsigned)CAP;
    const float* buf = cbuf + (size_t)ch * CAP;
    const int tid = threadIdx.x;

    __shared__ unsigned hA[NB1];
    __shared__ unsigned hB[256];
    __shared__ double   wsum[4];
    for (int j = tid; j < NB1; j += 256) hA[j] = 0u;
    __syncthreads();
    for (unsigned i = tid; i < cnt; i += 256) {
        const unsigned bt = __float_as_uint(buf[i]);
        atomicAdd(&hA[(bt >> 8) & 2047u], 1u);
    }
    __syncthreads();
    unsigned T2, rem2;
    select_counts<NB1>(hA, rem1[ch], T2, rem2);

    hB[tid] = 0u;
    __syncthreads();
    for (unsigned i = tid; i < cnt; i += 256) {
        const unsigned bt = __float_as_uint(buf[i]);
        if (((bt >> 8) & 2047u) == T2) atomicAdd(&hB[bt & 255u], 1u);
    }
    __syncthreads();
    unsigned T3, rem3;
    select_counts<256>(hB, rem2, T3, rem3);

    const float t = __uint_as_float((T1[ch] << 19) | (T2 << 8) | T3);
    double s = 0.0;
    for (unsigned i = tid; i < cnt; i += 256) {
        const float v = buf[i];
        if (v > t) s += (double)v;
    }
    for (int o = 32; o > 0; o >>= 1) s += __shfl_down(s, o);
    const int wid = tid >> 6, lane = tid & 63;
    if (lane == 0) wsum[wid] = s;
    __syncthreads();
    if (tid == 0) {
        const double stop = wsum[0] + wsum[1] + wsum[2] + wsum[3];
        const double nega = (sumAbove[ch] + stop + (double)rem3 * (double)t) / (double)k;
        contrib[ch] = (float)((double)posi[ch] + nega);
    }
}

__global__ void k_reduce(const float* __restrict__ contrib, float* __restrict__ out)
{
    double v = (double)contrib[threadIdx.x];
    for (int o = 32; o > 0; o >>= 1) v += __shfl_down(v, o);
    if (threadIdx.x == 0) out[0] = (float)(v / (double)BATCH);
}

// ---------------------------------------------------------------------------
extern "C" void kernel_launch(void* const* d_in, const int* in_sizes, int n_in,
                              void* d_out, int out_size, void* d_ws, size_t ws_size,
                              hipStream_t stream)
{
    (void)in_sizes; (void)n_in; (void)out_size; (void)ws_size;
    const float4* pred4 = (const float4*)d_in[0];
    const float4* reg4  = (const float4*)d_in[1];
    const float4* aff4  = (const float4*)d_in[2];

    char* w = (char*)d_ws;
    unsigned* h1c  = (unsigned*)w;                        // 64*2048 u32 = 512 KB
    unsigned* pcnt = h1c + (size_t)CH2 * NB1;
    float*    psum = (float*)(pcnt + CH2);
    unsigned* T1   = (unsigned*)(psum + CH2);
    unsigned* rem1 = T1 + CH2;
    unsigned* kk   = rem1 + CH2;
    float*    posi = (float*)(kk + CH2);
    float*    contrib = posi + CH2;
    unsigned* ccnt = (unsigned*)(contrib + CH2);
    double*   sumAbove = (double*)(ccnt + CH2);           // offset divisible by 8
    const size_t hdr_bytes = (size_t)((char*)(sumAbove + CH2) - w);  // ~527 KB

    float* cbuf = (float*)(w + ((size_t)1 << 20));        // 33.5 MB at +1 MB

    hipMemsetAsync(d_ws, 0, hdr_bytes, stream);

    dim3 grid(BX, BATCH);
    k_hist<<<grid, 256, 0, stream>>>(pred4, reg4, aff4, h1c, pcnt, psum);
    k_scan1<<<CH2, 256, 0, stream>>>(h1c, pcnt, psum, T1, rem1, kk, posi);
    k_compact<<<grid, 256, 0, stream>>>(pred4, reg4, aff4, T1, cbuf, ccnt, sumAbove);
    k_refine<<<CH2, 256, 0, stream>>>(cbuf, ccnt, T1, rem1, kk, posi, sumAbove, contrib);
    k_reduce<<<1, 64, 0, stream>>>(contrib, (float*)d_out);
}